// Round 4
// baseline (177.443 us; speedup 1.0000x reference)
//
#include <hip/hip_runtime.h>
#include <hip/hip_bf16.h>
#include <stdint.h>

#define M_DIM 4096
#define N_DIM 4096
#define K_DIM 4096
#define NH 128
#define NW 128
#define NKT 64   // K-tiles of BK=64

typedef short bf16x8 __attribute__((ext_vector_type(8)));
typedef short bf16x4 __attribute__((ext_vector_type(4)));
typedef float f32x4 __attribute__((ext_vector_type(4)));

#define MFMA(a, b, c) __builtin_amdgcn_mfma_f32_16x16x32_bf16((a), (b), (c), 0, 0, 0)

__device__ __forceinline__ short f2bf(float f) {
  union { float f; unsigned u; } c; c.f = f;
  unsigned u = c.u;
  unsigned r = (u + 0x7fffu + ((u >> 16) & 1u)) >> 16;  // RNE
  return (short)r;
}

// ---------------- kernel 1: per-32x32-block mask ----------------
__global__ __launch_bounds__(256) void k_block_mask(const int* __restrict__ mask,
                                                    const float* __restrict__ conv_bias,
                                                    int* __restrict__ bm) {
  const int bw = blockIdx.x, bh = blockIdx.y;
  const int t = threadIdx.x;
  const int row = t >> 3;
  const int c4 = (t & 7) << 2;
  const int4* p = (const int4*)(mask + (size_t)(bh * 32 + row) * K_DIM + bw * 32 + c4);
  int4 v = *p;
  int s = v.x + v.y + v.z + v.w;
#pragma unroll
  for (int off = 32; off > 0; off >>= 1) s += __shfl_down(s, off);
  __shared__ int red[4];
  if ((t & 63) == 0) red[t >> 6] = s;
  __syncthreads();
  if (t == 0) {
    float tot = (float)(red[0] + red[1] + red[2] + red[3]) + conv_bias[0];
    bm[bh * NW + bw] = (tot > 0.0f) ? 1 : 0;
  }
}

// ---------------- kernel 2: data f32 -> bf16 ----------------
__global__ __launch_bounds__(256) void k_cvt_data(const float* __restrict__ in,
                                                  short* __restrict__ ob) {
  size_t i = (size_t)blockIdx.x * 256 + threadIdx.x;
  f32x4 v = ((const f32x4*)in)[i];
  bf16x4 o;
  o[0] = f2bf(v[0]); o[1] = f2bf(v[1]); o[2] = f2bf(v[2]); o[3] = f2bf(v[3]);
  ((bf16x4*)ob)[i] = o;
}

// ---------------- kernel 3: weight f32 -> masked bf16 ----------------
__global__ __launch_bounds__(256) void k_cvt_weight(const float* __restrict__ w,
                                                    const int* __restrict__ bm,
                                                    short* __restrict__ ob) {
  size_t i = (size_t)blockIdx.x * 256 + threadIdx.x;
  int n = (int)(i >> 10);
  int k = ((int)i & 1023) << 2;
  float m = bm[((n >> 5) << 7) + (k >> 5)] ? 1.0f : 0.0f;
  f32x4 v = ((const f32x4*)w)[i];
  bf16x4 o;
  o[0] = f2bf(v[0] * m); o[1] = f2bf(v[1] * m);
  o[2] = f2bf(v[2] * m); o[3] = f2bf(v[3] * m);
  ((bf16x4*)ob)[i] = o;
}

// ---------------- kernel 4: 256x256 8-phase bf16 NT GEMM ----------------
// 8 waves (2Mx4N), BK=64 as 2 ks-slabs [256][32] (64B rows), double-buffered,
// K-loop unrolled x2 so ALL LDS addresses have compile-time buffer indices.
// Swizzle: physical colseg = logical ^ (row bits 2:1), applied on the
// pre-swizzled global SOURCE and on the ds_read address (both sides, rule 21).
// Even staging: 2 global_load_lds per phase; counted vmcnt(4) once per K-tile.
__global__ __launch_bounds__(512, 2) void k_gemm256(const short* __restrict__ Ab,
                                                    const short* __restrict__ Bb,
                                                    const float* __restrict__ bias,
                                                    float* __restrict__ out) {
  __shared__ short Asm[2][2][256][32];  // [buf][ks][row][colseg*8] 64 KB
  __shared__ short Bsm[2][2][256][32];  // 64 KB

  const int tid = threadIdx.x;
  const int wid = tid >> 6, lane = tid & 63;
  const int wr = wid >> 2, wc = wid & 3;
  const int r = lane & 15, g0 = lane >> 4;
  const int gs = g0 ^ ((r >> 1) & 3);      // swizzled col-seg for ds_read

  // XCD-aware swizzle: 256 wgs, 8 XCDs, 32/XCD (bijective since 256%8==0)
  const int swz = (blockIdx.x & 7) * 32 + (blockIdx.x >> 3);
  const int bx = swz & 15, by = swz >> 4;
  const int rowM = by * 256, colN = bx * 256;

  // staging geometry: 512 thr x 16B = one (h,ks) 8KB region, linear LDS dest
  const int srow = tid >> 2;                         // 0..127 within half
  const int sseg = (tid & 3) ^ ((tid >> 3) & 3);     // pre-swizzled source seg
  const int swave = wid * 512;                       // wave-uniform LDS base (shorts)

  const short* gA = Ab + (size_t)(rowM + srow) * K_DIM + sseg * 8;
  const short* gB = Bb + (size_t)(colN + srow) * K_DIM + sseg * 8;
  const size_t HOFF = (size_t)128 * K_DIM;

#define GLL(g, l)                                                            \
  __builtin_amdgcn_global_load_lds((const __attribute__((address_space(1))) void*)(g), \
                                   (__attribute__((address_space(3))) void*)(l), 16, 0, 0)
#define STA(BUF, kt, h, ks) GLL(gA + HOFF * (h) + (size_t)(kt) * 64 + (ks) * 32, \
                                &Asm[BUF][ks][(h) * 128][0] + swave)
#define STB(BUF, kt, h, ks) GLL(gB + HOFF * (h) + (size_t)(kt) * 64 + (ks) * 32, \
                                &Bsm[BUF][ks][(h) * 128][0] + swave)

#define LDA(BUF, ks, m) (*(const bf16x8*)&Asm[BUF][ks][wr * 128 + (m) * 16 + r][gs * 8])
#define LDB(BUF, ks, n) (*(const bf16x8*)&Bsm[BUF][ks][wc * 64 + (n) * 16 + r][gs * 8])
#define LDA8(BUF, ks)                                                        \
  a[0] = LDA(BUF, ks, 0); a[1] = LDA(BUF, ks, 1); a[2] = LDA(BUF, ks, 2);    \
  a[3] = LDA(BUF, ks, 3); a[4] = LDA(BUF, ks, 4); a[5] = LDA(BUF, ks, 5);    \
  a[6] = LDA(BUF, ks, 6); a[7] = LDA(BUF, ks, 7);
#define MF8(nn, bb)                                                          \
  acc[0][nn] = MFMA(a[0], bb, acc[0][nn]); acc[1][nn] = MFMA(a[1], bb, acc[1][nn]); \
  acc[2][nn] = MFMA(a[2], bb, acc[2][nn]); acc[3][nn] = MFMA(a[3], bb, acc[3][nn]); \
  acc[4][nn] = MFMA(a[4], bb, acc[4][nn]); acc[5][nn] = MFMA(a[5], bb, acc[5][nn]); \
  acc[6][nn] = MFMA(a[6], bb, acc[6][nn]); acc[7][nn] = MFMA(a[7], bb, acc[7][nn]);
#define BAR __builtin_amdgcn_s_barrier()
#define PRIO1 __builtin_amdgcn_s_setprio(1)
#define PRIO0 __builtin_amdgcn_s_setprio(0)

// One K-tile (4 phases, 2 staging loads per phase, 16 MFMA per phase).
// Staging-liveness: P2's stage overwrites Asm[BUF][ks0] (last read in P0,
// retired by P1-end barrier); P3's overwrites ks1 (read in P2, retired by
// P2-end barrier). vmcnt(4) at tile end = B(u+1)+A(u+1) landed, A(u+2) flying.
#define TILE(BUF, NB, u, SB, SA, VM)                                         \
  {                                                                          \
    bf16x8 a[8], p, q;                                                       \
    LDA8(BUF, 0);                                                            \
    p = LDB(BUF, 0, 0); q = LDB(BUF, 0, 1);                                  \
    if (SB) { STB(NB, (u) + 1, 0, 0); STB(NB, (u) + 1, 0, 1); }              \
    BAR; PRIO1; MF8(0, p); MF8(1, q); PRIO0; BAR;                            \
    p = LDB(BUF, 0, 2); q = LDB(BUF, 0, 3);                                  \
    if (SB) { STB(NB, (u) + 1, 1, 0); STB(NB, (u) + 1, 1, 1); }              \
    BAR; PRIO1; MF8(2, p); MF8(3, q); PRIO0; BAR;                            \
    LDA8(BUF, 1);                                                            \
    p = LDB(BUF, 1, 0); q = LDB(BUF, 1, 1);                                  \
    if (SA) { STA(BUF, (u) + 2, 0, 0); STA(BUF, (u) + 2, 1, 0); }            \
    BAR; PRIO1; MF8(0, p); MF8(1, q); PRIO0; BAR;                            \
    p = LDB(BUF, 1, 2); q = LDB(BUF, 1, 3);                                  \
    if (SA) { STA(BUF, (u) + 2, 0, 1); STA(BUF, (u) + 2, 1, 1); }            \
    BAR; PRIO1; MF8(2, p); MF8(3, q); PRIO0;                                 \
    asm volatile("s_waitcnt vmcnt(" #VM ")" ::: "memory");                   \
    BAR;                                                                     \
  }

  f32x4 acc[8][4];
#pragma unroll
  for (int m = 0; m < 8; ++m)
#pragma unroll
    for (int n = 0; n < 4; ++n) acc[m][n] = (f32x4){0.f, 0.f, 0.f, 0.f};

  // prologue: A0 (4), B0 (4), A1 (4); wait oldest 8 -> A0,B0 landed
  STA(0, 0, 0, 0); STA(0, 0, 1, 0); STA(0, 0, 0, 1); STA(0, 0, 1, 1);
  STB(0, 0, 0, 0); STB(0, 0, 1, 0); STB(0, 0, 0, 1); STB(0, 0, 1, 1);
  STA(1, 1, 0, 0); STA(1, 1, 1, 0); STA(1, 1, 0, 1); STA(1, 1, 1, 1);
  asm volatile("s_waitcnt vmcnt(4)" ::: "memory");
  BAR;

#pragma unroll 1
  for (int u = 0; u < NKT - 2; u += 2) {
    TILE(0, 1, u, 1, 1, 4);
    TILE(1, 0, u + 1, 1, 1, 4);
  }
  // peeled tail: tile 62 (stage B63 only, full drain), tile 63 (no staging)
  TILE(0, 1, NKT - 2, 1, 0, 0);
  TILE(1, 0, NKT - 1, 0, 0, 0);

  // epilogue: C/D layout col=lane&15 (=r), row=(lane>>4)*4+j (=g0*4+j)
  const int orow = rowM + wr * 128;
  const int ocol = colN + wc * 64;
#pragma unroll
  for (int n = 0; n < 4; ++n) {
    int col = ocol + n * 16 + r;
    float bz = bias[col];
#pragma unroll
    for (int m = 0; m < 8; ++m) {
      int row0 = orow + m * 16 + g0 * 4;
#pragma unroll
      for (int j = 0; j < 4; ++j)
        out[(size_t)(row0 + j) * N_DIM + col] = acc[m][n][j] + bz;
    }
  }
#undef TILE
#undef GLL
#undef STA
#undef STB
#undef LDA
#undef LDB
#undef LDA8
#undef MF8
#undef BAR
#undef PRIO1
#undef PRIO0
}

// ---------------- fallback (ws too small): naive fp32 ----------------
__global__ __launch_bounds__(256) void k_naive(const float* __restrict__ A,
                                               const float* __restrict__ W,
                                               const float* __restrict__ bias,
                                               const int* __restrict__ bm,
                                               float* __restrict__ out) {
  int col = blockIdx.x * 16 + (threadIdx.x & 15);
  int row = blockIdx.y * 16 + (threadIdx.x >> 4);
  float s = 0.f;
  for (int kb = 0; kb < K_DIM / 32; ++kb) {
    if (bm[(col >> 5) * NW + kb]) {
      int kbase = kb * 32;
#pragma unroll 8
      for (int k = 0; k < 32; ++k)
        s += A[(size_t)row * K_DIM + kbase + k] * W[(size_t)col * K_DIM + kbase + k];
    }
  }
  out[(size_t)row * N_DIM + col] = s + bias[col];
}

extern "C" void kernel_launch(void* const* d_in, const int* in_sizes, int n_in,
                              void* d_out, int out_size, void* d_ws, size_t ws_size,
                              hipStream_t stream) {
  const float* data = (const float*)d_in[0];
  const float* weight = (const float*)d_in[1];
  const float* bias = (const float*)d_in[2];
  const int* mask = (const int*)d_in[3];
  const float* conv_bias = (const float*)d_in[4];
  float* out = (float*)d_out;

  int* bm = (int*)d_ws;
  const size_t off_a = 65536;
  const size_t off_b = off_a + (size_t)M_DIM * K_DIM * 2;
  const size_t needed = off_b + (size_t)N_DIM * K_DIM * 2;

  k_block_mask<<<dim3(NW, NH), 256, 0, stream>>>(mask, conv_bias, bm);

  if (ws_size >= needed) {
    short* Abf = (short*)((char*)d_ws + off_a);
    short* Wbf = (short*)((char*)d_ws + off_b);
    k_cvt_data<<<dim3((M_DIM * (K_DIM / 4)) / 256), 256, 0, stream>>>(data, Abf);
    k_cvt_weight<<<dim3((N_DIM * (K_DIM / 4)) / 256), 256, 0, stream>>>(weight, bm, Wbf);
    k_gemm256<<<dim3(256), 512, 0, stream>>>(Abf, Wbf, bias, out);
  } else {
    k_naive<<<dim3(N_DIM / 16, M_DIM / 16), 256, 0, stream>>>(data, weight, bias, bm, out);
  }
}

// Round 5
// 160.140 us; speedup vs baseline: 1.1080x; 1.1080x over previous
//
#include <hip/hip_runtime.h>
#include <hip/hip_bf16.h>
#include <stdint.h>

#define M_DIM 4096
#define N_DIM 4096
#define K_DIM 4096
#define NH 128
#define NW 128
#define NKT 64   // K-tiles of BK=64

typedef short bf16x8 __attribute__((ext_vector_type(8)));
typedef short bf16x4 __attribute__((ext_vector_type(4)));
typedef float f32x4 __attribute__((ext_vector_type(4)));

#define MFMA(a, b, c) __builtin_amdgcn_mfma_f32_16x16x32_bf16((a), (b), (c), 0, 0, 0)

__device__ __forceinline__ short f2bf(float f) {
  union { float f; unsigned u; } c; c.f = f;
  unsigned u = c.u;
  unsigned r = (u + 0x7fffu + ((u >> 16) & 1u)) >> 16;  // RNE
  return (short)r;
}

// ---------------- kernel 1: per-32x32-block mask ----------------
__global__ __launch_bounds__(256) void k_block_mask(const int* __restrict__ mask,
                                                    const float* __restrict__ conv_bias,
                                                    int* __restrict__ bm) {
  const int bw = blockIdx.x, bh = blockIdx.y;
  const int t = threadIdx.x;
  const int row = t >> 3;
  const int c4 = (t & 7) << 2;
  const int4* p = (const int4*)(mask + (size_t)(bh * 32 + row) * K_DIM + bw * 32 + c4);
  int4 v = *p;
  int s = v.x + v.y + v.z + v.w;
#pragma unroll
  for (int off = 32; off > 0; off >>= 1) s += __shfl_down(s, off);
  __shared__ int red[4];
  if ((t & 63) == 0) red[t >> 6] = s;
  __syncthreads();
  if (t == 0) {
    float tot = (float)(red[0] + red[1] + red[2] + red[3]) + conv_bias[0];
    bm[bh * NW + bw] = (tot > 0.0f) ? 1 : 0;
  }
}

// ---------------- kernel 2: data f32 -> bf16 ----------------
__global__ __launch_bounds__(256) void k_cvt_data(const float* __restrict__ in,
                                                  short* __restrict__ ob) {
  size_t i = (size_t)blockIdx.x * 256 + threadIdx.x;
  f32x4 v = ((const f32x4*)in)[i];
  bf16x4 o;
  o[0] = f2bf(v[0]); o[1] = f2bf(v[1]); o[2] = f2bf(v[2]); o[3] = f2bf(v[3]);
  ((bf16x4*)ob)[i] = o;
}

// ---------------- kernel 3: weight f32 -> masked bf16 ----------------
__global__ __launch_bounds__(256) void k_cvt_weight(const float* __restrict__ w,
                                                    const int* __restrict__ bm,
                                                    short* __restrict__ ob) {
  size_t i = (size_t)blockIdx.x * 256 + threadIdx.x;
  int n = (int)(i >> 10);
  int k = ((int)i & 1023) << 2;
  float m = bm[((n >> 5) << 7) + (k >> 5)] ? 1.0f : 0.0f;
  f32x4 v = ((const f32x4*)w)[i];
  bf16x4 o;
  o[0] = f2bf(v[0] * m); o[1] = f2bf(v[1] * m);
  o[2] = f2bf(v[2] * m); o[3] = f2bf(v[3] * m);
  ((bf16x4*)ob)[i] = o;
}

// ---------------- kernel 4: 256x256 pipelined 4-phase bf16 NT GEMM ----------
// 8 waves (2Mx4N). BK=64 as 2 ks-slabs [256][32], double-buffered LDS.
// Register pipeline: each phase issues the NEXT phase's ds_reads, then runs
// the CURRENT phase's 16 MFMA (compiler emits counted lgkmcnt -> LDS drain
// overlaps matrix pipe). One s_barrier per phase. Counted vmcnt(6)@P0-end,
// vmcnt(4)@P2-end; cross-tile operand reads only after the P3 barrier.
__global__ __launch_bounds__(512, 2) void k_gemm256(const short* __restrict__ Ab,
                                                    const short* __restrict__ Bb,
                                                    const float* __restrict__ bias,
                                                    float* __restrict__ out) {
  __shared__ short Asm[2][2][256][32];  // [buf][ks][row][colseg*8] 64 KB
  __shared__ short Bsm[2][2][256][32];  // 64 KB

  const int tid = threadIdx.x;
  const int wid = tid >> 6, lane = tid & 63;
  const int wr = wid >> 2, wc = wid & 3;
  const int r = lane & 15, g0 = lane >> 4;
  const int gs = g0 ^ ((r >> 1) & 3);      // swizzled col-seg for ds_read

  // XCD-aware swizzle: 256 wgs, 8 XCDs, 32/XCD (bijective since 256%8==0)
  const int swz = (blockIdx.x & 7) * 32 + (blockIdx.x >> 3);
  const int bx = swz & 15, by = swz >> 4;
  const int rowM = by * 256, colN = bx * 256;

  // staging geometry: 512 thr x 16B = one (h,ks) 8KB region, linear LDS dest
  const int srow = tid >> 2;                         // 0..127 within half
  const int sseg = (tid & 3) ^ ((tid >> 3) & 3);     // pre-swizzled source seg
  const int swave = wid * 512;                       // wave-uniform LDS base (shorts)

  const short* gA = Ab + (size_t)(rowM + srow) * K_DIM + sseg * 8;
  const short* gB = Bb + (size_t)(colN + srow) * K_DIM + sseg * 8;
  const size_t HOFF = (size_t)128 * K_DIM;

#define GLL(g, l)                                                            \
  __builtin_amdgcn_global_load_lds((const __attribute__((address_space(1))) void*)(g), \
                                   (__attribute__((address_space(3))) void*)(l), 16, 0, 0)
#define STA(BUF, kt, h, ks) GLL(gA + HOFF * (h) + (size_t)(kt) * 64 + (ks) * 32, \
                                &Asm[BUF][ks][(h) * 128][0] + swave)
#define STB(BUF, kt, h, ks) GLL(gB + HOFF * (h) + (size_t)(kt) * 64 + (ks) * 32, \
                                &Bsm[BUF][ks][(h) * 128][0] + swave)

#define LDA(BUF, ks, m) (*(const bf16x8*)&Asm[BUF][ks][wr * 128 + (m) * 16 + r][gs * 8])
#define LDB(BUF, ks, n) (*(const bf16x8*)&Bsm[BUF][ks][wc * 64 + (n) * 16 + r][gs * 8])

#define MF8(AR, nn, bb)                                                      \
  acc[0][nn] = MFMA(AR[0], bb, acc[0][nn]); acc[1][nn] = MFMA(AR[1], bb, acc[1][nn]); \
  acc[2][nn] = MFMA(AR[2], bb, acc[2][nn]); acc[3][nn] = MFMA(AR[3], bb, acc[3][nn]); \
  acc[4][nn] = MFMA(AR[4], bb, acc[4][nn]); acc[5][nn] = MFMA(AR[5], bb, acc[5][nn]); \
  acc[6][nn] = MFMA(AR[6], bb, acc[6][nn]); acc[7][nn] = MFMA(AR[7], bb, acc[7][nn]);

#define BAR __builtin_amdgcn_s_barrier()
#define SB0 __builtin_amdgcn_sched_barrier(0)
#define PRIO1 __builtin_amdgcn_s_setprio(1)
#define PRIO0 __builtin_amdgcn_s_setprio(0)
#define VMW_(N) asm volatile("s_waitcnt vmcnt(" #N ")" ::: "memory")
#define VMW(N) VMW_(N)

// One K-tile, 4 phases. Phase = [BAR; sched_bar; reads for NEXT phase;
// MFMA CUR (lgkm counted by compiler); stage; optional vmcnt].
// Reg roles: aX=ks0 A-frags, aY=ks1; bA=b01 pair, bB=b23 pair (alternate ks).
// Stage slots: P0/P1 -> B(u+1) ks0/ks1; P2/P3 -> A(u+2) ks0/ks1.
// WAR-safety of stages: each stage slot is preceded (via this tile's barriers)
// by the MFMA that last consumed the target region (reads complete pre-MFMA).
#define TILE(BUF, NB, u, SB, SA, SR, VM0, VM2)                               \
  {                                                                          \
    /* P0: uses aX,bA (ks0 n01) */                                           \
    BAR; SB0;                                                                \
    bB[0] = LDB(BUF, 0, 2); bB[1] = LDB(BUF, 0, 3);                          \
    aY[0] = LDA(BUF, 1, 0); aY[1] = LDA(BUF, 1, 1);                          \
    aY[2] = LDA(BUF, 1, 2); aY[3] = LDA(BUF, 1, 3);                          \
    PRIO1; MF8(aX, 0, bA[0]); MF8(aX, 1, bA[1]); PRIO0;                      \
    if (SB) { STB(NB, (u) + 1, 0, 0); STB(NB, (u) + 1, 1, 0); }              \
    VMW(VM0);                                                                \
    /* P1: uses aX,bB (ks0 n23) */                                           \
    BAR; SB0;                                                                \
    aY[4] = LDA(BUF, 1, 4); aY[5] = LDA(BUF, 1, 5);                          \
    aY[6] = LDA(BUF, 1, 6); aY[7] = LDA(BUF, 1, 7);                          \
    bA[0] = LDB(BUF, 1, 0); bA[1] = LDB(BUF, 1, 1);                          \
    PRIO1; MF8(aX, 2, bB[0]); MF8(aX, 3, bB[1]); PRIO0;                      \
    if (SB) { STB(NB, (u) + 1, 0, 1); STB(NB, (u) + 1, 1, 1); }              \
    /* P2: uses aY,bA (ks1 n01) */                                           \
    BAR; SB0;                                                                \
    bB[0] = LDB(BUF, 1, 2); bB[1] = LDB(BUF, 1, 3);                          \
    PRIO1; MF8(aY, 0, bA[0]); MF8(aY, 1, bA[1]); PRIO0;                      \
    if (SA) { STA(BUF, (u) + 2, 0, 0); STA(BUF, (u) + 2, 1, 0); }            \
    VMW(VM2);                                                                \
    /* P3: uses aY,bB (ks1 n23); cross-tile prefetch after this barrier */   \
    BAR; SB0;                                                                \
    if (SR) {                                                                \
      aX[0] = LDA(NB, 0, 0); aX[1] = LDA(NB, 0, 1);                          \
      aX[2] = LDA(NB, 0, 2); aX[3] = LDA(NB, 0, 3);                          \
      aX[4] = LDA(NB, 0, 4); aX[5] = LDA(NB, 0, 5);                          \
      aX[6] = LDA(NB, 0, 6); aX[7] = LDA(NB, 0, 7);                          \
      bA[0] = LDB(NB, 0, 0); bA[1] = LDB(NB, 0, 1);                          \
    }                                                                        \
    PRIO1; MF8(aY, 2, bB[0]); MF8(aY, 3, bB[1]); PRIO0;                      \
    if (SA) { STA(BUF, (u) + 2, 0, 1); STA(BUF, (u) + 2, 1, 1); }            \
  }

  f32x4 acc[8][4];
#pragma unroll
  for (int m = 0; m < 8; ++m)
#pragma unroll
    for (int n = 0; n < 4; ++n) acc[m][n] = (f32x4){0.f, 0.f, 0.f, 0.f};

  bf16x8 aX[8], aY[8], bA[2], bB[2];

  // prologue stages, ordered to reproduce the steady-state vmcnt FIFO window:
  // [A0ks0 A0ks1 B0ks0 B0ks1 | A1ks0 A1ks1]; vmcnt(4) -> A0,B0 landed.
  STA(0, 0, 0, 0); STA(0, 0, 1, 0); STA(0, 0, 0, 1); STA(0, 0, 1, 1);
  STB(0, 0, 0, 0); STB(0, 0, 1, 0); STB(0, 0, 0, 1); STB(0, 0, 1, 1);
  STA(1, 1, 0, 0); STA(1, 1, 1, 0); STA(1, 1, 0, 1); STA(1, 1, 1, 1);
  VMW(4);
  BAR; SB0;
  // preload tile-0 P0 operands
  aX[0] = LDA(0, 0, 0); aX[1] = LDA(0, 0, 1); aX[2] = LDA(0, 0, 2);
  aX[3] = LDA(0, 0, 3); aX[4] = LDA(0, 0, 4); aX[5] = LDA(0, 0, 5);
  aX[6] = LDA(0, 0, 6); aX[7] = LDA(0, 0, 7);
  bA[0] = LDB(0, 0, 0); bA[1] = LDB(0, 0, 1);

#pragma unroll 1
  for (int u = 0; u < NKT - 2; u += 2) {
    TILE(0, 1, u, 1, 1, 1, 6, 4);
    TILE(1, 0, u + 1, 1, 1, 1, 6, 4);
  }
  // tile 62: stage B(63) only; vmcnt(2)@P2-end forces B63ks0 landed (no A-stage
  // in flight to pad the window). tile 63: no stages, drain before P1 reads.
  TILE(0, 1, NKT - 2, 1, 0, 1, 6, 2);
  TILE(1, 0, NKT - 1, 0, 0, 0, 0, 0);

  // epilogue: C/D layout col=lane&15 (=r), row=(lane>>4)*4+j (=g0*4+j)
  const int orow = rowM + wr * 128;
  const int ocol = colN + wc * 64;
#pragma unroll
  for (int n = 0; n < 4; ++n) {
    int col = ocol + n * 16 + r;
    float bz = bias[col];
#pragma unroll
    for (int m = 0; m < 8; ++m) {
      int row0 = orow + m * 16 + g0 * 4;
#pragma unroll
      for (int j = 0; j < 4; ++j)
        out[(size_t)(row0 + j) * N_DIM + col] = acc[m][n][j] + bz;
    }
  }
#undef TILE
#undef GLL
#undef STA
#undef STB
#undef LDA
#undef LDB
#undef MF8
#undef BAR
#undef SB0
#undef PRIO1
#undef PRIO0
#undef VMW
#undef VMW_
}

// ---------------- fallback (ws too small): naive fp32 ----------------
__global__ __launch_bounds__(256) void k_naive(const float* __restrict__ A,
                                               const float* __restrict__ W,
                                               const float* __restrict__ bias,
                                               const int* __restrict__ bm,
                                               float* __restrict__ out) {
  int col = blockIdx.x * 16 + (threadIdx.x & 15);
  int row = blockIdx.y * 16 + (threadIdx.x >> 4);
  float s = 0.f;
  for (int kb = 0; kb < K_DIM / 32; ++kb) {
    if (bm[(col >> 5) * NW + kb]) {
      int kbase = kb * 32;
#pragma unroll 8
      for (int k = 0; k < 32; ++k)
        s += A[(size_t)row * K_DIM + kbase + k] * W[(size_t)col * K_DIM + kbase + k];
    }
  }
  out[(size_t)row * N_DIM + col] = s + bias[col];
}

extern "C" void kernel_launch(void* const* d_in, const int* in_sizes, int n_in,
                              void* d_out, int out_size, void* d_ws, size_t ws_size,
                              hipStream_t stream) {
  const float* data = (const float*)d_in[0];
  const float* weight = (const float*)d_in[1];
  const float* bias = (const float*)d_in[2];
  const int* mask = (const int*)d_in[3];
  const float* conv_bias = (const float*)d_in[4];
  float* out = (float*)d_out;

  int* bm = (int*)d_ws;
  const size_t off_a = 65536;
  const size_t off_b = off_a + (size_t)M_DIM * K_DIM * 2;
  const size_t needed = off_b + (size_t)N_DIM * K_DIM * 2;

  k_block_mask<<<dim3(NW, NH), 256, 0, stream>>>(mask, conv_bias, bm);

  if (ws_size >= needed) {
    short* Abf = (short*)((char*)d_ws + off_a);
    short* Wbf = (short*)((char*)d_ws + off_b);
    k_cvt_data<<<dim3((M_DIM * (K_DIM / 4)) / 256), 256, 0, stream>>>(data, Abf);
    k_cvt_weight<<<dim3((N_DIM * (K_DIM / 4)) / 256), 256, 0, stream>>>(weight, bm, Wbf);
    k_gemm256<<<dim3(256), 512, 0, stream>>>(Abf, Wbf, bias, out);
  } else {
    k_naive<<<dim3(N_DIM / 16, M_DIM / 16), 256, 0, stream>>>(data, weight, bias, bm, out);
  }
}

// Round 6
// 149.983 us; speedup vs baseline: 1.1831x; 1.0677x over previous
//
#include <hip/hip_runtime.h>
#include <hip/hip_bf16.h>
#include <stdint.h>

#define M_DIM 4096
#define N_DIM 4096
#define K_DIM 4096
#define NH 128
#define NW 128
#define NKT 64   // K-tiles of BK=64

typedef short bf16x8 __attribute__((ext_vector_type(8)));
typedef short bf16x4 __attribute__((ext_vector_type(4)));
typedef float f32x4 __attribute__((ext_vector_type(4)));

#define MFMA(a, b, c) __builtin_amdgcn_mfma_f32_16x16x32_bf16((a), (b), (c), 0, 0, 0)

__device__ __forceinline__ short f2bf(float f) {
  union { float f; unsigned u; } c; c.f = f;
  unsigned u = c.u;
  unsigned r = (u + 0x7fffu + ((u >> 16) & 1u)) >> 16;  // RNE
  return (short)r;
}

// ---------------- kernel 1: per-32x32-block mask ----------------
__global__ __launch_bounds__(256) void k_block_mask(const int* __restrict__ mask,
                                                    const float* __restrict__ conv_bias,
                                                    int* __restrict__ bm) {
  const int bw = blockIdx.x, bh = blockIdx.y;
  const int t = threadIdx.x;
  const int row = t >> 3;
  const int c4 = (t & 7) << 2;
  const int4* p = (const int4*)(mask + (size_t)(bh * 32 + row) * K_DIM + bw * 32 + c4);
  int4 v = *p;
  int s = v.x + v.y + v.z + v.w;
#pragma unroll
  for (int off = 32; off > 0; off >>= 1) s += __shfl_down(s, off);
  __shared__ int red[4];
  if ((t & 63) == 0) red[t >> 6] = s;
  __syncthreads();
  if (t == 0) {
    float tot = (float)(red[0] + red[1] + red[2] + red[3]) + conv_bias[0];
    bm[bh * NW + bw] = (tot > 0.0f) ? 1 : 0;
  }
}

// ---------------- kernel 2: data f32 -> bf16 ----------------
__global__ __launch_bounds__(256) void k_cvt_data(const float* __restrict__ in,
                                                  short* __restrict__ ob) {
  size_t i = (size_t)blockIdx.x * 256 + threadIdx.x;
  f32x4 v = ((const f32x4*)in)[i];
  bf16x4 o;
  o[0] = f2bf(v[0]); o[1] = f2bf(v[1]); o[2] = f2bf(v[2]); o[3] = f2bf(v[3]);
  ((bf16x4*)ob)[i] = o;
}

// ---------------- kernel 3: weight f32 -> masked bf16 ----------------
__global__ __launch_bounds__(256) void k_cvt_weight(const float* __restrict__ w,
                                                    const int* __restrict__ bm,
                                                    short* __restrict__ ob) {
  size_t i = (size_t)blockIdx.x * 256 + threadIdx.x;
  int n = (int)(i >> 10);
  int k = ((int)i & 1023) << 2;
  float m = bm[((n >> 5) << 7) + (k >> 5)] ? 1.0f : 0.0f;
  f32x4 v = ((const f32x4*)w)[i];
  bf16x4 o;
  o[0] = f2bf(v[0] * m); o[1] = f2bf(v[1] * m);
  o[2] = f2bf(v[2] * m); o[3] = f2bf(v[3] * m);
  ((bf16x4*)ob)[i] = o;
}

// ---------------- kernel 4: 256x256 pipelined 4-phase bf16 NT GEMM ----------
// As round 5 (register pipeline, counted vmcnt, XOR swizzle, XCD swizzle),
// plus BLOCK-SPARSE MFMA SKIP: each phase's 16-MFMA cluster covers exactly one
// 32x32 mask block per wave (P0=(nb0,2u) P1=(nb1,2u) P2=(nb0,2u+1)
// P3=(nb1,2u+1)); inactive blocks' B-fragments are exactly 0 in Wbf, so
// skipping their MFMAs is numerically identical (~50% MFMA work cut).
// Mask bits preloaded per-wave as 4x64-bit ballot words BEFORE any staging
// (sched_barrier keeps the vmcnt FIFO composition exact).
__global__ __launch_bounds__(512, 2) void k_gemm256(const short* __restrict__ Ab,
                                                    const short* __restrict__ Bb,
                                                    const float* __restrict__ bias,
                                                    const int* __restrict__ bm,
                                                    float* __restrict__ out) {
  __shared__ short Asm[2][2][256][32];  // [buf][ks][row][colseg*8] 64 KB
  __shared__ short Bsm[2][2][256][32];  // 64 KB

  const int tid = threadIdx.x;
  const int wid = tid >> 6, lane = tid & 63;
  const int wr = wid >> 2, wc = wid & 3;
  const int r = lane & 15, g0 = lane >> 4;
  const int gs = g0 ^ ((r >> 1) & 3);      // swizzled col-seg for ds_read

  // XCD-aware swizzle: 256 wgs, 8 XCDs, 32/XCD (bijective since 256%8==0)
  const int swz = (blockIdx.x & 7) * 32 + (blockIdx.x >> 3);
  const int bx = swz & 15, by = swz >> 4;
  const int rowM = by * 256, colN = bx * 256;

  // staging geometry: 512 thr x 16B = one (h,ks) 8KB region, linear LDS dest
  const int srow = tid >> 2;                         // 0..127 within half
  const int sseg = (tid & 3) ^ ((tid >> 3) & 3);     // pre-swizzled source seg
  const int swave = wid * 512;                       // wave-uniform LDS base (shorts)

  const short* gA = Ab + (size_t)(rowM + srow) * K_DIM + sseg * 8;
  const short* gB = Bb + (size_t)(colN + srow) * K_DIM + sseg * 8;
  const size_t HOFF = (size_t)128 * K_DIM;

  // ---- per-wave mask bits: rows nb0, nb0+1 of bm, 128 kc each -> 4x u64 ----
  const int nb0 = (colN >> 5) + wc * 2;
  unsigned long long w00, w01, w10, w11;
  {
    const int* bp = bm + nb0 * NW;
    int v0 = bp[lane], v1 = bp[64 + lane], v2 = bp[128 + lane], v3 = bp[192 + lane];
    w00 = __ballot(v0 != 0); w01 = __ballot(v1 != 0);
    w10 = __ballot(v2 != 0); w11 = __ballot(v3 != 0);
  }
  __builtin_amdgcn_sched_barrier(0);  // mask loads fully retired before staging

#define BT(lo, hi, kc) ((int)((((kc) & 64) ? (hi) : (lo)) >> ((kc) & 63)) & 1)

#define GLL(g, l)                                                            \
  __builtin_amdgcn_global_load_lds((const __attribute__((address_space(1))) void*)(g), \
                                   (__attribute__((address_space(3))) void*)(l), 16, 0, 0)
#define STA(BUF, kt, h, ks) GLL(gA + HOFF * (h) + (size_t)(kt) * 64 + (ks) * 32, \
                                &Asm[BUF][ks][(h) * 128][0] + swave)
#define STB(BUF, kt, h, ks) GLL(gB + HOFF * (h) + (size_t)(kt) * 64 + (ks) * 32, \
                                &Bsm[BUF][ks][(h) * 128][0] + swave)

#define LDA(BUF, ks, m) (*(const bf16x8*)&Asm[BUF][ks][wr * 128 + (m) * 16 + r][gs * 8])
#define LDB(BUF, ks, n) (*(const bf16x8*)&Bsm[BUF][ks][wc * 64 + (n) * 16 + r][gs * 8])

#define MF8(AR, nn, bb)                                                      \
  acc[0][nn] = MFMA(AR[0], bb, acc[0][nn]); acc[1][nn] = MFMA(AR[1], bb, acc[1][nn]); \
  acc[2][nn] = MFMA(AR[2], bb, acc[2][nn]); acc[3][nn] = MFMA(AR[3], bb, acc[3][nn]); \
  acc[4][nn] = MFMA(AR[4], bb, acc[4][nn]); acc[5][nn] = MFMA(AR[5], bb, acc[5][nn]); \
  acc[6][nn] = MFMA(AR[6], bb, acc[6][nn]); acc[7][nn] = MFMA(AR[7], bb, acc[7][nn]);

#define BAR __builtin_amdgcn_s_barrier()
#define SB0 __builtin_amdgcn_sched_barrier(0)
#define PRIO1 __builtin_amdgcn_s_setprio(1)
#define PRIO0 __builtin_amdgcn_s_setprio(0)
#define VMW_(N) asm volatile("s_waitcnt vmcnt(" #N ")" ::: "memory")
#define VMW(N) VMW_(N)

// One K-tile, 4 phases; E0..E3 = active-bits for the block each phase covers.
// Reads/stages/barriers/vmcnts are UNCONDITIONAL (schedule & FIFO unchanged);
// only the MFMA clusters are skipped for inactive blocks.
#define TILE(BUF, NB, u, SB, SA, SR, VM0, VM2, E0, E1, E2, E3)               \
  {                                                                          \
    /* P0: uses aX,bA (ks0 n01) -> block (nb0, 2u) */                        \
    BAR; SB0;                                                                \
    bB[0] = LDB(BUF, 0, 2); bB[1] = LDB(BUF, 0, 3);                          \
    aY[0] = LDA(BUF, 1, 0); aY[1] = LDA(BUF, 1, 1);                          \
    aY[2] = LDA(BUF, 1, 2); aY[3] = LDA(BUF, 1, 3);                          \
    if (E0) { PRIO1; MF8(aX, 0, bA[0]); MF8(aX, 1, bA[1]); PRIO0; }          \
    if (SB) { STB(NB, (u) + 1, 0, 0); STB(NB, (u) + 1, 1, 0); }              \
    VMW(VM0);                                                                \
    /* P1: uses aX,bB (ks0 n23) -> block (nb1, 2u) */                        \
    BAR; SB0;                                                                \
    aY[4] = LDA(BUF, 1, 4); aY[5] = LDA(BUF, 1, 5);                          \
    aY[6] = LDA(BUF, 1, 6); aY[7] = LDA(BUF, 1, 7);                          \
    bA[0] = LDB(BUF, 1, 0); bA[1] = LDB(BUF, 1, 1);                          \
    if (E1) { PRIO1; MF8(aX, 2, bB[0]); MF8(aX, 3, bB[1]); PRIO0; }          \
    if (SB) { STB(NB, (u) + 1, 0, 1); STB(NB, (u) + 1, 1, 1); }              \
    /* P2: uses aY,bA (ks1 n01) -> block (nb0, 2u+1) */                      \
    BAR; SB0;                                                                \
    bB[0] = LDB(BUF, 1, 2); bB[1] = LDB(BUF, 1, 3);                          \
    if (E2) { PRIO1; MF8(aY, 0, bA[0]); MF8(aY, 1, bA[1]); PRIO0; }          \
    if (SA) { STA(BUF, (u) + 2, 0, 0); STA(BUF, (u) + 2, 1, 0); }            \
    VMW(VM2);                                                                \
    /* P3: uses aY,bB (ks1 n23) -> block (nb1, 2u+1) */                      \
    BAR; SB0;                                                                \
    if (SR) {                                                                \
      aX[0] = LDA(NB, 0, 0); aX[1] = LDA(NB, 0, 1);                          \
      aX[2] = LDA(NB, 0, 2); aX[3] = LDA(NB, 0, 3);                          \
      aX[4] = LDA(NB, 0, 4); aX[5] = LDA(NB, 0, 5);                          \
      aX[6] = LDA(NB, 0, 6); aX[7] = LDA(NB, 0, 7);                          \
      bA[0] = LDB(NB, 0, 0); bA[1] = LDB(NB, 0, 1);                          \
    }                                                                        \
    if (E3) { PRIO1; MF8(aY, 2, bB[0]); MF8(aY, 3, bB[1]); PRIO0; }          \
    if (SA) { STA(BUF, (u) + 2, 0, 1); STA(BUF, (u) + 2, 1, 1); }            \
  }

  f32x4 acc[8][4];
#pragma unroll
  for (int m = 0; m < 8; ++m)
#pragma unroll
    for (int n = 0; n < 4; ++n) acc[m][n] = (f32x4){0.f, 0.f, 0.f, 0.f};

  bf16x8 aX[8], aY[8], bA[2], bB[2];

  // prologue stages, ordered to reproduce the steady-state vmcnt FIFO window:
  // [A0ks0 A0ks1 B0ks0 B0ks1 | A1ks0 A1ks1]; vmcnt(4) -> A0,B0 landed.
  STA(0, 0, 0, 0); STA(0, 0, 1, 0); STA(0, 0, 0, 1); STA(0, 0, 1, 1);
  STB(0, 0, 0, 0); STB(0, 0, 1, 0); STB(0, 0, 0, 1); STB(0, 0, 1, 1);
  STA(1, 1, 0, 0); STA(1, 1, 1, 0); STA(1, 1, 0, 1); STA(1, 1, 1, 1);
  VMW(4);
  BAR; SB0;
  // preload tile-0 P0 operands
  aX[0] = LDA(0, 0, 0); aX[1] = LDA(0, 0, 1); aX[2] = LDA(0, 0, 2);
  aX[3] = LDA(0, 0, 3); aX[4] = LDA(0, 0, 4); aX[5] = LDA(0, 0, 5);
  aX[6] = LDA(0, 0, 6); aX[7] = LDA(0, 0, 7);
  bA[0] = LDB(0, 0, 0); bA[1] = LDB(0, 0, 1);

#pragma unroll 1
  for (int u = 0; u < NKT - 2; u += 2) {
    const int kc = 2 * u;
    TILE(0, 1, u, 1, 1, 1, 6, 4,
         BT(w00, w01, kc),     BT(w10, w11, kc),
         BT(w00, w01, kc + 1), BT(w10, w11, kc + 1));
    TILE(1, 0, u + 1, 1, 1, 1, 6, 4,
         BT(w00, w01, kc + 2), BT(w10, w11, kc + 2),
         BT(w00, w01, kc + 3), BT(w10, w11, kc + 3));
  }
  // peeled tails: tile 62 (kc 124,125), tile 63 (kc 126,127)
  TILE(0, 1, NKT - 2, 1, 0, 1, 6, 2,
       BT(w00, w01, 124), BT(w10, w11, 124),
       BT(w00, w01, 125), BT(w10, w11, 125));
  TILE(1, 0, NKT - 1, 0, 0, 0, 0, 0,
       BT(w00, w01, 126), BT(w10, w11, 126),
       BT(w00, w01, 127), BT(w10, w11, 127));

  // epilogue: C/D layout col=lane&15 (=r), row=(lane>>4)*4+j (=g0*4+j)
  const int orow = rowM + wr * 128;
  const int ocol = colN + wc * 64;
#pragma unroll
  for (int n = 0; n < 4; ++n) {
    int col = ocol + n * 16 + r;
    float bz = bias[col];
#pragma unroll
    for (int m = 0; m < 8; ++m) {
      int row0 = orow + m * 16 + g0 * 4;
#pragma unroll
      for (int j = 0; j < 4; ++j)
        out[(size_t)(row0 + j) * N_DIM + col] = acc[m][n][j] + bz;
    }
  }
#undef TILE
#undef GLL
#undef STA
#undef STB
#undef LDA
#undef LDB
#undef MF8
#undef BAR
#undef SB0
#undef PRIO1
#undef PRIO0
#undef VMW
#undef VMW_
#undef BT
}

// ---------------- fallback (ws too small): naive fp32 ----------------
__global__ __launch_bounds__(256) void k_naive(const float* __restrict__ A,
                                               const float* __restrict__ W,
                                               const float* __restrict__ bias,
                                               const int* __restrict__ bm,
                                               float* __restrict__ out) {
  int col = blockIdx.x * 16 + (threadIdx.x & 15);
  int row = blockIdx.y * 16 + (threadIdx.x >> 4);
  float s = 0.f;
  for (int kb = 0; kb < K_DIM / 32; ++kb) {
    if (bm[(col >> 5) * NW + kb]) {
      int kbase = kb * 32;
#pragma unroll 8
      for (int k = 0; k < 32; ++k)
        s += A[(size_t)row * K_DIM + kbase + k] * W[(size_t)col * K_DIM + kbase + k];
    }
  }
  out[(size_t)row * N_DIM + col] = s + bias[col];
}

extern "C" void kernel_launch(void* const* d_in, const int* in_sizes, int n_in,
                              void* d_out, int out_size, void* d_ws, size_t ws_size,
                              hipStream_t stream) {
  const float* data = (const float*)d_in[0];
  const float* weight = (const float*)d_in[1];
  const float* bias = (const float*)d_in[2];
  const int* mask = (const int*)d_in[3];
  const float* conv_bias = (const float*)d_in[4];
  float* out = (float*)d_out;

  int* bm = (int*)d_ws;
  const size_t off_a = 65536;
  const size_t off_b = off_a + (size_t)M_DIM * K_DIM * 2;
  const size_t needed = off_b + (size_t)N_DIM * K_DIM * 2;

  k_block_mask<<<dim3(NW, NH), 256, 0, stream>>>(mask, conv_bias, bm);

  if (ws_size >= needed) {
    short* Abf = (short*)((char*)d_ws + off_a);
    short* Wbf = (short*)((char*)d_ws + off_b);
    k_cvt_data<<<dim3((M_DIM * (K_DIM / 4)) / 256), 256, 0, stream>>>(data, Abf);
    k_cvt_weight<<<dim3((N_DIM * (K_DIM / 4)) / 256), 256, 0, stream>>>(weight, bm, Wbf);
    k_gemm256<<<dim3(256), 512, 0, stream>>>(Abf, Wbf, bias, bm, out);
  } else {
    k_naive<<<dim3(N_DIM / 16, M_DIM / 16), 256, 0, stream>>>(data, weight, bias, bm, out);
  }
}